// Round 11
// baseline (195.332 us; speedup 1.0000x reference)
//
#include <hip/hip_runtime.h>

typedef __attribute__((ext_vector_type(4))) float f4;
typedef __attribute__((ext_vector_type(4))) float f32x4;
typedef __attribute__((ext_vector_type(8))) __bf16 bf8;
typedef __attribute__((ext_vector_type(8))) unsigned short us8;

#define NB 64
#define LSEQ 40
#define D_DIM 768
#define NPATCH 576
#define SEQ 617
#define K_DIM 768
#define M_DIM (NB * NPATCH)   // 36864

static __device__ __forceinline__ unsigned short f2bf(float f) {
    union { float f; unsigned u; } v; v.f = f;
    unsigned r = v.u + 0x7FFFu + ((v.u >> 16) & 1u);
    return (unsigned short)(r >> 16);
}

#define MFMA16(a, b, c) __builtin_amdgcn_mfma_f32_16x16x32_bf16((a), (b), (c), 0, 0, 0)

// ---- prep: convert_w (plain row-major bf16) + text rows + CLS/masks ----
// blocks [0,288): conv_w f32 -> bf16 (no swizzle: GEMM reads it direct)
//        [288,928): text gather+LN+mod
//        [928,1275): CLS rows + masks
__global__ __launch_bounds__(256) void prep_kernel(
    const float* __restrict__ cw, unsigned short* __restrict__ wo,
    const int* __restrict__ ids, const int* __restrict__ tti,
    const float* __restrict__ we, const float* __restrict__ pe,
    const float* __restrict__ tke, const float* __restrict__ g,
    const float* __restrict__ bb, const float* __restrict__ mod,
    const float* __restrict__ cls, const int* __restrict__ am,
    float* __restrict__ out) {
    int blk = blockIdx.x;
    if (blk < 288) {
        int t = blk * 256 + threadIdx.x;   // 73728 threads x 8 elems
        int off = t * 8;
        f4 a = *(const f4*)(cw + off);
        f4 b = *(const f4*)(cw + off + 4);
        us8 r;
        r[0]=f2bf(a[0]); r[1]=f2bf(a[1]); r[2]=f2bf(a[2]); r[3]=f2bf(a[3]);
        r[4]=f2bf(b[0]); r[5]=f2bf(b[1]); r[6]=f2bf(b[2]); r[7]=f2bf(b[3]);
        *(us8*)(wo + off) = r;
    } else if (blk < 928) {
        int row = (blk - 288) * 4 + (threadIdx.x >> 6);   // 2560 rows
        int lane = threadIdx.x & 63;
        int b = row / 40, l = row % 40;
        const float* wp = we + (size_t)ids[row] * 768;
        const float* pp = pe + l * 768;
        const float* tp = tke + (size_t)tti[row] * 768;
        f4 x[3];
        float s = 0.f, q = 0.f;
#pragma unroll
        for (int j = 0; j < 3; ++j) {
            int d = j * 256 + lane * 4;
            f4 v = *(const f4*)(wp + d);
            f4 v2 = *(const f4*)(pp + d);
            f4 v3 = *(const f4*)(tp + d);
            v = v + v2 + v3;
            x[j] = v;
            s += v[0] + v[1] + v[2] + v[3];
            q += v[0]*v[0] + v[1]*v[1] + v[2]*v[2] + v[3]*v[3];
        }
#pragma unroll
        for (int o = 32; o > 0; o >>= 1) { s += __shfl_xor(s, o); q += __shfl_xor(q, o); }
        float mean = s * (1.0f / 768.0f);
        float var = q * (1.0f / 768.0f) - mean * mean;
        float rstd = rsqrtf(var + 1e-12f);
        float* op = out + ((size_t)b * SEQ + 1 + l) * 768;
#pragma unroll
        for (int j = 0; j < 3; ++j) {
            int d = j * 256 + lane * 4;
            f4 gg = *(const f4*)(g + d);
            f4 bv = *(const f4*)(bb + d);
            f4 mm = *(const f4*)(mod + d);
            f4 r = (x[j] - mean) * rstd * gg + bv + mm;
            *(f4*)(op + d) = r;
        }
    } else {
        int t = (blk - 928) * 256 + threadIdx.x;
        if (t < NB * 768) {
            int b = t / 768, d = t % 768;
            out[(size_t)b * SEQ * 768 + d] = cls[d];
        } else if (t < NB * 768 + NB * SEQ) {
            int i = t - NB * 768;
            int b = i / SEQ, s = i % SEQ;
            float v = 1.0f;
            if (s >= 1 && s <= LSEQ) v = (float)am[b * LSEQ + s - 1];
            out[(size_t)NB * SEQ * 768 + i] = v;
        }
    }
}

// ---- LDS-free patch GEMM: 128x128 tile, 4 waves, each 64x64 out ----
// No __shared__, no barriers, no staging. Each wave loads its MFMA
// fragments directly: A from pixel_values (f32, cvt in-reg; one frag-load
// instruction's 64 lanes cover 2 image rows x 16 consecutive patches x
// full 64B j-range = perfectly coalesced), B from row-major bf16 W
// (1.1 MB, L2-resident). Waves free-run; compiler pipelines the
// barrier-free dataflow. acc = 64 AGPR/wave; ~174 total regs -> 2+
// blocks/CU. k = c*256 + i*16 + j decode per frag (kt,ks,hk):
// c=kt>>2, i=(kt&3)*4+ks*2+(hk>>1), j=(hk&1)*8.
__global__ __launch_bounds__(256, 2) void gemm_patch(
    const float* __restrict__ px, const __bf16* __restrict__ W,
    const float* __restrict__ conv_b, const float* __restrict__ vis_pos,
    const float* __restrict__ mod, float* __restrict__ out) {
    const int tid = threadIdx.x;
    const int w = tid >> 6, lane = tid & 63;

    // bijective XCD remap: 1728 blocks = 8 XCDs * 216; consecutive gwi
    // share tile_m (6 n-tiles of one px panel on the same XCD's L2).
    int lid = blockIdx.x;
    int gwi = (lid & 7) * 216 + (lid >> 3);
    const int tile_n = (gwi % 6) * 128;
    const int tile_m = (gwi / 6) * 128;
    const int wm = w >> 1, wn = w & 1;
    const int wr = wm * 64, wc = wn * 64;

    const int rsel = lane & 15;
    const int hk = lane >> 4;

    // per-lane A row pointers (4 mi-frags; fixed across K)
    const float* apx[4];
#pragma unroll
    for (int mi = 0; mi < 4; ++mi) {
        int gm = tile_m + wr + mi * 16 + rsel;
        int bimg = gm / 576, p = gm % 576;
        int ph = p / 24, pw = p % 24;
        apx[mi] = px + (size_t)bimg * 442368
                     + (size_t)(ph * 16 + (hk >> 1)) * 384
                     + pw * 16 + (hk & 1) * 8;
    }
    // per-lane B row pointers (4 ni-frags)
    const __bf16* bW[4];
#pragma unroll
    for (int ni = 0; ni < 4; ++ni)
        bW[ni] = W + (size_t)(tile_n + wc + ni * 16 + rsel) * 768 + hk * 8;

    f32x4 acc[4][4] = {};

    for (int kt = 0; kt < 12; ++kt) {
        const int aoff = (kt >> 2) * 147456 + (kt & 3) * 4 * 384;  // f32 elems
        const int koff = kt * 64;                                   // bf16 elems

        bf8 a[4][2], b[4][2];
#pragma unroll
        for (int mi = 0; mi < 4; ++mi)
#pragma unroll
            for (int ks = 0; ks < 2; ++ks) {
                const float* s = apx[mi] + aoff + ks * 768;  // ks*2 rows
                f4 lo = *(const f4*)s;
                f4 hi = *(const f4*)(s + 4);
                bf8 v;
#pragma unroll
                for (int q = 0; q < 4; ++q) {
                    v[q]     = (__bf16)lo[q];
                    v[4 + q] = (__bf16)hi[q];
                }
                a[mi][ks] = v;
            }
#pragma unroll
        for (int ni = 0; ni < 4; ++ni)
#pragma unroll
            for (int ks = 0; ks < 2; ++ks)
                b[ni][ks] = *(const bf8*)(bW[ni] + koff + ks * 32);

#pragma unroll
        for (int mi = 0; mi < 4; ++mi)
#pragma unroll
            for (int ni = 0; ni < 4; ++ni) {
                acc[mi][ni] = MFMA16(a[mi][0], b[ni][0], acc[mi][ni]);
                acc[mi][ni] = MFMA16(a[mi][1], b[ni][1], acc[mi][ni]);
            }
    }

    // ---- epilogue: hoisted div, per-ni const folds ----
    const int lr = (lane >> 4) * 4;
    const int lc = lane & 15;
    int gnv[4]; float cv[4];
#pragma unroll
    for (int ni = 0; ni < 4; ++ni) {
        gnv[ni] = tile_n + wc + ni * 16 + lc;
        cv[ni] = conv_b[gnv[ni]] + mod[768 + gnv[ni]];
    }
#pragma unroll
    for (int mi = 0; mi < 4; ++mi) {
        int gm0 = tile_m + wr + mi * 16 + lr;
        int bimg0 = gm0 / 576;
        int pp0 = gm0 - bimg0 * 576;
#pragma unroll
        for (int r = 0; r < 4; ++r) {
            int bimg = bimg0, pp2 = pp0 + r;
            if (pp2 >= 576) { bimg++; pp2 -= 576; }
            const float* vp = vis_pos + (size_t)(pp2 + 1) * 768;
            float* op = out + ((size_t)bimg * SEQ + 1 + LSEQ + pp2) * 768;
#pragma unroll
            for (int ni = 0; ni < 4; ++ni)
                op[gnv[ni]] = acc[mi][ni][r] + cv[ni] + vp[gnv[ni]];
        }
    }
}

extern "C" void kernel_launch(void* const* d_in, const int* in_sizes, int n_in,
                              void* d_out, int out_size, void* d_ws, size_t ws_size,
                              hipStream_t stream) {
    const int*   ids  = (const int*)d_in[0];
    const int*   am   = (const int*)d_in[1];
    const int*   tti  = (const int*)d_in[2];
    const float* px   = (const float*)d_in[3];
    const float* we   = (const float*)d_in[5];
    const float* pe   = (const float*)d_in[6];
    const float* tke  = (const float*)d_in[7];
    const float* lng  = (const float*)d_in[8];
    const float* lnb  = (const float*)d_in[9];
    const float* cw   = (const float*)d_in[10];
    const float* cb   = (const float*)d_in[11];
    const float* cls  = (const float*)d_in[12];
    const float* vpos = (const float*)d_in[13];
    const float* mod  = (const float*)d_in[14];
    float* out = (float*)d_out;

    __bf16* Wbf = (__bf16*)d_ws;

    prep_kernel<<<1275, 256, 0, stream>>>(cw, (unsigned short*)Wbf, ids, tti,
                                          we, pe, tke, lng, lnb, mod, cls, am, out);
    gemm_patch<<<1728, 256, 0, stream>>>(px, Wbf, cb, vpos, mod, out);
}

// Round 12
// 181.817 us; speedup vs baseline: 1.0743x; 1.0743x over previous
//
#include <hip/hip_runtime.h>

typedef __attribute__((ext_vector_type(4))) float f4;
typedef __attribute__((ext_vector_type(4))) float f32x4;
typedef __attribute__((ext_vector_type(8))) __bf16 bf8;
typedef __attribute__((ext_vector_type(8))) unsigned short us8;

#define NB 64
#define LSEQ 40
#define D_DIM 768
#define NPATCH 576
#define SEQ 617
#define K_DIM 768
#define M_DIM (NB * NPATCH)   // 36864

static __device__ __forceinline__ unsigned short f2bf(float f) {
    union { float f; unsigned u; } v; v.f = f;
    unsigned r = v.u + 0x7FFFu + ((v.u >> 16) & 1u);
    return (unsigned short)(r >> 16);
}

#define MFMA16(a, b, c) __builtin_amdgcn_mfma_f32_16x16x32_bf16((a), (b), (c), 0, 0, 0)

// ---- prep: convert_w (plain row-major bf16) + text rows + CLS/masks ----
// blocks [0,288): conv_w f32 -> bf16 (no swizzle: GEMM reads it direct)
//        [288,928): text gather+LN+mod
//        [928,1275): CLS rows + masks
__global__ __launch_bounds__(256) void prep_kernel(
    const float* __restrict__ cw, unsigned short* __restrict__ wo,
    const int* __restrict__ ids, const int* __restrict__ tti,
    const float* __restrict__ we, const float* __restrict__ pe,
    const float* __restrict__ tke, const float* __restrict__ g,
    const float* __restrict__ bb, const float* __restrict__ mod,
    const float* __restrict__ cls, const int* __restrict__ am,
    float* __restrict__ out) {
    int blk = blockIdx.x;
    if (blk < 288) {
        int t = blk * 256 + threadIdx.x;   // 73728 threads x 8 elems
        int off = t * 8;
        f4 a = *(const f4*)(cw + off);
        f4 b = *(const f4*)(cw + off + 4);
        us8 r;
        r[0]=f2bf(a[0]); r[1]=f2bf(a[1]); r[2]=f2bf(a[2]); r[3]=f2bf(a[3]);
        r[4]=f2bf(b[0]); r[5]=f2bf(b[1]); r[6]=f2bf(b[2]); r[7]=f2bf(b[3]);
        *(us8*)(wo + off) = r;
    } else if (blk < 928) {
        int row = (blk - 288) * 4 + (threadIdx.x >> 6);   // 2560 rows
        int lane = threadIdx.x & 63;
        int b = row / 40, l = row % 40;
        const float* wp = we + (size_t)ids[row] * 768;
        const float* pp = pe + l * 768;
        const float* tp = tke + (size_t)tti[row] * 768;
        f4 x[3];
        float s = 0.f, q = 0.f;
#pragma unroll
        for (int j = 0; j < 3; ++j) {
            int d = j * 256 + lane * 4;
            f4 v = *(const f4*)(wp + d);
            f4 v2 = *(const f4*)(pp + d);
            f4 v3 = *(const f4*)(tp + d);
            v = v + v2 + v3;
            x[j] = v;
            s += v[0] + v[1] + v[2] + v[3];
            q += v[0]*v[0] + v[1]*v[1] + v[2]*v[2] + v[3]*v[3];
        }
#pragma unroll
        for (int o = 32; o > 0; o >>= 1) { s += __shfl_xor(s, o); q += __shfl_xor(q, o); }
        float mean = s * (1.0f / 768.0f);
        float var = q * (1.0f / 768.0f) - mean * mean;
        float rstd = rsqrtf(var + 1e-12f);
        float* op = out + ((size_t)b * SEQ + 1 + l) * 768;
#pragma unroll
        for (int j = 0; j < 3; ++j) {
            int d = j * 256 + lane * 4;
            f4 gg = *(const f4*)(g + d);
            f4 bv = *(const f4*)(bb + d);
            f4 mm = *(const f4*)(mod + d);
            f4 r = (x[j] - mean) * rstd * gg + bv + mm;
            *(f4*)(op + d) = r;
        }
    } else {
        int t = (blk - 928) * 256 + threadIdx.x;
        if (t < NB * 768) {
            int b = t / 768, d = t % 768;
            out[(size_t)b * SEQ * 768 + d] = cls[d];
        } else if (t < NB * 768 + NB * SEQ) {
            int i = t - NB * 768;
            int b = i / SEQ, s = i % SEQ;
            float v = 1.0f;
            if (s >= 1 && s <= LSEQ) v = (float)am[b * LSEQ + s - 1];
            out[(size_t)NB * SEQ * 768 + i] = v;
        }
    }
}

// ---- LDS-free patch GEMM: 128x128 tile, 4 waves, each 64x64 out ----
// No __shared__, no barriers, no staging. A direct from pixel_values
// (f32, cvt in-reg; one frag-load's 64 lanes cover 2 image rows x 16
// consecutive patches x full 64B j-range = perfectly coalesced), B direct
// from row-major bf16 W (1.1 MB, L2-resident).
// R12 fix: kt loop FULLY UNROLLED -> the scheduler hoists loads across
// K-steps (software pipelining); R11's rolled loop allocated only 64 VGPR
// and serialized load->wait->MFMA per step (222 us, MfmaUtil 7.8%).
// k = c*256 + i*16 + j decode: c=kt>>2, i=(kt&3)*4+ks*2+(hk>>1),
// j=(hk&1)*8  ->  k_local = ks*32 + hk*8 (matches B's koff indexing).
__global__ __launch_bounds__(256, 2) void gemm_patch(
    const float* __restrict__ px, const __bf16* __restrict__ W,
    const float* __restrict__ conv_b, const float* __restrict__ vis_pos,
    const float* __restrict__ mod, float* __restrict__ out) {
    const int tid = threadIdx.x;
    const int w = tid >> 6, lane = tid & 63;

    // bijective XCD remap: 1728 blocks = 8 XCDs * 216; consecutive gwi
    // share tile_m (6 n-tiles of one px panel on the same XCD's L2,
    // temporally adjacent).
    int lid = blockIdx.x;
    int gwi = (lid & 7) * 216 + (lid >> 3);
    const int tile_n = (gwi % 6) * 128;
    const int tile_m = (gwi / 6) * 128;
    const int wm = w >> 1, wn = w & 1;
    const int wr = wm * 64, wc = wn * 64;

    const int rsel = lane & 15;
    const int hk = lane >> 4;

    // per-lane A row pointers (4 mi-frags; fixed across K)
    const float* apx[4];
#pragma unroll
    for (int mi = 0; mi < 4; ++mi) {
        int gm = tile_m + wr + mi * 16 + rsel;
        int bimg = gm / 576, p = gm % 576;
        int ph = p / 24, pw = p % 24;
        apx[mi] = px + (size_t)bimg * 442368
                     + (size_t)(ph * 16 + (hk >> 1)) * 384
                     + pw * 16 + (hk & 1) * 8;
    }
    // per-lane B row pointers (4 ni-frags)
    const __bf16* bW[4];
#pragma unroll
    for (int ni = 0; ni < 4; ++ni)
        bW[ni] = W + (size_t)(tile_n + wc + ni * 16 + rsel) * 768 + hk * 8;

    f32x4 acc[4][4] = {};

#pragma unroll
    for (int kt = 0; kt < 12; ++kt) {
        const int aoff = (kt >> 2) * 147456 + (kt & 3) * 4 * 384;  // f32 elems
        const int koff = kt * 64;                                   // bf16 elems

        bf8 a[4][2], b[4][2];
#pragma unroll
        for (int mi = 0; mi < 4; ++mi)
#pragma unroll
            for (int ks = 0; ks < 2; ++ks) {
                const float* s = apx[mi] + aoff + ks * 768;  // ks*2 rows
                f4 lo = *(const f4*)s;
                f4 hi = *(const f4*)(s + 4);
                bf8 v;
#pragma unroll
                for (int q = 0; q < 4; ++q) {
                    v[q]     = (__bf16)lo[q];
                    v[4 + q] = (__bf16)hi[q];
                }
                a[mi][ks] = v;
            }
#pragma unroll
        for (int ni = 0; ni < 4; ++ni)
#pragma unroll
            for (int ks = 0; ks < 2; ++ks)
                b[ni][ks] = *(const bf8*)(bW[ni] + koff + ks * 32);

#pragma unroll
        for (int mi = 0; mi < 4; ++mi)
#pragma unroll
            for (int ni = 0; ni < 4; ++ni) {
                acc[mi][ni] = MFMA16(a[mi][0], b[ni][0], acc[mi][ni]);
                acc[mi][ni] = MFMA16(a[mi][1], b[ni][1], acc[mi][ni]);
            }
    }

    // ---- epilogue: hoisted div, per-ni const folds ----
    const int lr = (lane >> 4) * 4;
    const int lc = lane & 15;
    int gnv[4]; float cv[4];
#pragma unroll
    for (int ni = 0; ni < 4; ++ni) {
        gnv[ni] = tile_n + wc + ni * 16 + lc;
        cv[ni] = conv_b[gnv[ni]] + mod[768 + gnv[ni]];
    }
#pragma unroll
    for (int mi = 0; mi < 4; ++mi) {
        int gm0 = tile_m + wr + mi * 16 + lr;
        int bimg0 = gm0 / 576;
        int pp0 = gm0 - bimg0 * 576;
#pragma unroll
        for (int r = 0; r < 4; ++r) {
            int bimg = bimg0, pp2 = pp0 + r;
            if (pp2 >= 576) { bimg++; pp2 -= 576; }
            const float* vp = vis_pos + (size_t)(pp2 + 1) * 768;
            float* op = out + ((size_t)bimg * SEQ + 1 + LSEQ + pp2) * 768;
#pragma unroll
            for (int ni = 0; ni < 4; ++ni)
                op[gnv[ni]] = acc[mi][ni][r] + cv[ni] + vp[gnv[ni]];
        }
    }
}

extern "C" void kernel_launch(void* const* d_in, const int* in_sizes, int n_in,
                              void* d_out, int out_size, void* d_ws, size_t ws_size,
                              hipStream_t stream) {
    const int*   ids  = (const int*)d_in[0];
    const int*   am   = (const int*)d_in[1];
    const int*   tti  = (const int*)d_in[2];
    const float* px   = (const float*)d_in[3];
    const float* we   = (const float*)d_in[5];
    const float* pe   = (const float*)d_in[6];
    const float* tke  = (const float*)d_in[7];
    const float* lng  = (const float*)d_in[8];
    const float* lnb  = (const float*)d_in[9];
    const float* cw   = (const float*)d_in[10];
    const float* cb   = (const float*)d_in[11];
    const float* cls  = (const float*)d_in[12];
    const float* vpos = (const float*)d_in[13];
    const float* mod  = (const float*)d_in[14];
    float* out = (float*)d_out;

    __bf16* Wbf = (__bf16*)d_ws;

    prep_kernel<<<1275, 256, 0, stream>>>(cw, (unsigned short*)Wbf, ids, tti,
                                          we, pe, tke, lng, lnb, mod, cls, am, out);
    gemm_patch<<<1728, 256, 0, stream>>>(px, Wbf, cb, vpos, mod, out);
}

// Round 13
// 119.526 us; speedup vs baseline: 1.6342x; 1.5212x over previous
//
#include <hip/hip_runtime.h>

typedef __attribute__((ext_vector_type(4))) float f4;
typedef __attribute__((ext_vector_type(4))) float f32x4;
typedef __attribute__((ext_vector_type(8))) __bf16 bf8;
typedef __attribute__((ext_vector_type(8))) unsigned short us8;

#define NB 64
#define LSEQ 40
#define D_DIM 768
#define NPATCH 576
#define SEQ 617
#define K_DIM 768
#define M_DIM (NB * NPATCH)   // 36864
#define GEMM_LDS 65536

static __device__ __forceinline__ unsigned short f2bf(float f) {
    union { float f; unsigned u; } v; v.f = f;
    unsigned r = v.u + 0x7FFFu + ((v.u >> 16) & 1u);
    return (unsigned short)(r >> 16);
}

static __device__ __forceinline__ void gload_lds16(const void* g, void* l) {
    __builtin_amdgcn_global_load_lds(
        (const __attribute__((address_space(1))) unsigned int*)g,
        (__attribute__((address_space(3))) unsigned int*)l,
        16, 0, 0);
}

#define MFMA16(a, b, c) __builtin_amdgcn_mfma_f32_16x16x32_bf16((a), (b), (c), 0, 0, 0)

// ---- prep: convert_w (chunk-swizzled bf16) + text rows + CLS/masks ----
// stored[n][blk][c] = logical[n][blk][c ^ (n&7)], 16B chunks, 128B blocks.
__global__ __launch_bounds__(256) void prep_kernel(
    const float* __restrict__ cw, unsigned short* __restrict__ wo,
    const int* __restrict__ ids, const int* __restrict__ tti,
    const float* __restrict__ we, const float* __restrict__ pe,
    const float* __restrict__ tke, const float* __restrict__ g,
    const float* __restrict__ bb, const float* __restrict__ mod,
    const float* __restrict__ cls, const int* __restrict__ am,
    float* __restrict__ out) {
    int blk = blockIdx.x;
    if (blk < 288) {
        int t = blk * 256 + threadIdx.x;   // 73728 chunk-threads
        int cs = t % 96, n = t / 96;
        int blk8 = cs >> 3, c = cs & 7;
        int cl = (blk8 << 3) | (c ^ (n & 7));
        const float* s = cw + (size_t)n * 768 + cl * 8;
        f4 a = *(const f4*)s;
        f4 b = *(const f4*)(s + 4);
        us8 r;
        r[0]=f2bf(a[0]); r[1]=f2bf(a[1]); r[2]=f2bf(a[2]); r[3]=f2bf(a[3]);
        r[4]=f2bf(b[0]); r[5]=f2bf(b[1]); r[6]=f2bf(b[2]); r[7]=f2bf(b[3]);
        *(us8*)(wo + (size_t)n * 768 + cs * 8) = r;
    } else if (blk < 928) {
        int row = (blk - 288) * 4 + (threadIdx.x >> 6);   // 2560 rows
        int lane = threadIdx.x & 63;
        int b = row / 40, l = row % 40;
        const float* wp = we + (size_t)ids[row] * 768;
        const float* pp = pe + l * 768;
        const float* tp = tke + (size_t)tti[row] * 768;
        f4 x[3];
        float s = 0.f, q = 0.f;
#pragma unroll
        for (int j = 0; j < 3; ++j) {
            int d = j * 256 + lane * 4;
            f4 v = *(const f4*)(wp + d);
            f4 v2 = *(const f4*)(pp + d);
            f4 v3 = *(const f4*)(tp + d);
            v = v + v2 + v3;
            x[j] = v;
            s += v[0] + v[1] + v[2] + v[3];
            q += v[0]*v[0] + v[1]*v[1] + v[2]*v[2] + v[3]*v[3];
        }
#pragma unroll
        for (int o = 32; o > 0; o >>= 1) { s += __shfl_xor(s, o); q += __shfl_xor(q, o); }
        float mean = s * (1.0f / 768.0f);
        float var = q * (1.0f / 768.0f) - mean * mean;
        float rstd = rsqrtf(var + 1e-12f);
        float* op = out + ((size_t)b * SEQ + 1 + l) * 768;
#pragma unroll
        for (int j = 0; j < 3; ++j) {
            int d = j * 256 + lane * 4;
            f4 gg = *(const f4*)(g + d);
            f4 bv = *(const f4*)(bb + d);
            f4 mm = *(const f4*)(mod + d);
            f4 r = (x[j] - mean) * rstd * gg + bv + mm;
            *(f4*)(op + d) = r;
        }
    } else {
        int t = (blk - 928) * 256 + threadIdx.x;
        if (t < NB * 768) {
            int b = t / 768, d = t % 768;
            out[(size_t)b * SEQ * 768 + d] = cls[d];
        } else if (t < NB * 768 + NB * SEQ) {
            int i = t - NB * 768;
            int b = i / SEQ, s = i % SEQ;
            float v = 1.0f;
            if (s >= 1 && s <= LSEQ) v = (float)am[b * LSEQ + s - 1];
            out[(size_t)NB * SEQ * 768 + i] = v;
        }
    }
}

// ---- fused patch GEMM: 128x128 tile, BK=64, 4 waves, 64KB LDS ----
// R10 skeleton (proven) at half the tile: 64KB LDS -> 2 blocks/CU, so
// barrier/drain stalls of one block overlap the other block's compute
// (m114 mechanism), and grid 1728 = 6.75 blocks/CU kills the 1-block/CU
// dispatch-tail waste of the 256-sq config (432 blocks = 256+176 batches).
// Per tile t: LOAD_A px(t+1) + STAGE_B(t+1) -> ds_read frags -> 32 MFMA
// per wave -> WRITE_A (auto vmcnt wait) -> __syncthreads.
// A: each thread stages 2 image rows (16 f32 each) of its patch row,
// swizzled us8 writes; B: gload_lds from pre-swizzled W; reads XOR-match.
__global__ __launch_bounds__(256, 2) void gemm_patch(
    const float* __restrict__ px, const __bf16* __restrict__ W,
    const float* __restrict__ conv_b, const float* __restrict__ vis_pos,
    const float* __restrict__ mod, float* __restrict__ out) {
    extern __shared__ __align__(16) char smem[];   // 64 KB
    char* Ab0 = smem;            // A buffers: 128 rows x 128 B
    char* Ab1 = smem + 16384;
    char* Bb0 = smem + 32768;    // B buffers
    char* Bb1 = smem + 49152;

    const int tid = threadIdx.x;
    const int w = tid >> 6, lane = tid & 63;

    // bijective XCD remap: 1728 blocks = 8 XCDs * 216; consecutive gwi
    // share tile_m (6 n-sharers of one px panel on one XCD's L2).
    int lid = blockIdx.x;
    int gwi = (lid & 7) * 216 + (lid >> 3);
    const int tile_n = (gwi % 6) * 128;
    const int tile_m = (gwi / 6) * 128;
    const int wr = (w >> 1) * 64, wc = (w & 1) * 64;

    f32x4 acc[4][4] = {};
    const char* Bb = (const char*)W;
    const int rsel = lane & 15;
    const int hk = lane >> 4;

    // ---- A-staging lane geometry: 2 threads per A row ----
    const int arow = tid >> 1;           // A-tile row (patch) this thread stages
    const int half = tid & 1;            // which pair of image rows
    int agm = tile_m + arow;
    int abimg = agm / 576, ap = agm % 576;
    int aph = ap / 24, apw = ap % 24;
    const float* pxrow = px + (size_t)abimg * 442368
                            + (size_t)(aph * 16) * 384 + apw * 16;

    f4 areg[2][4];
    auto LOAD_A = [&](int kt) {
        int c = kt >> 2, i0 = (kt & 3) << 2;
#pragma unroll
        for (int rep = 0; rep < 2; ++rep) {
            int i = i0 + half * 2 + rep;
            const float* s = pxrow + (size_t)c * 147456 + i * 384;
#pragma unroll
            for (int q = 0; q < 4; ++q) areg[rep][q] = *(const f4*)(s + q * 4);
        }
    };
    auto WRITE_A = [&](char* dst) {
#pragma unroll
        for (int rep = 0; rep < 2; ++rep) {
            int il = half * 2 + rep;         // i_local in [0,4)
            us8 h0, h1;
#pragma unroll
            for (int q = 0; q < 2; ++q) {
                h0[q*4+0]=f2bf(areg[rep][q][0]); h0[q*4+1]=f2bf(areg[rep][q][1]);
                h0[q*4+2]=f2bf(areg[rep][q][2]); h0[q*4+3]=f2bf(areg[rep][q][3]);
                h1[q*4+0]=f2bf(areg[rep][q+2][0]); h1[q*4+1]=f2bf(areg[rep][q+2][1]);
                h1[q*4+2]=f2bf(areg[rep][q+2][2]); h1[q*4+3]=f2bf(areg[rep][q+2][3]);
            }
            int cc0 = il * 2;                // k_local chunk = i_local*2 + {0,1}
            *(us8*)(dst + arow * 128 + ((cc0    ) ^ (arow & 7)) * 16) = h0;
            *(us8*)(dst + arow * 128 + ((cc0 + 1) ^ (arow & 7)) * 16) = h1;
        }
    };
    auto STAGE_B = [&](char* lbase, int kt) {
#pragma unroll
        for (int i = 0; i < 4; ++i) {
            int uoff = i * 4096 + (w << 10);   // wave-uniform, covers 16KB
            int loff = uoff + (lane << 4);
            int row = loff >> 7, col = loff & 127;
            gload_lds16(Bb + (size_t)(tile_n + row) * 1536 + kt * 128 + col,
                        lbase + uoff);
        }
    };

    // prologue: tile 0
    LOAD_A(0);
    STAGE_B(Bb0, 0);
    WRITE_A(Ab0);            // compiler inserts vmcnt wait for areg
    __syncthreads();         // drains B gload_lds + A ds_writes

    for (int t = 0; t < 12; ++t) {
        char* Ac = (t & 1) ? Ab1 : Ab0;
        char* Bc = (t & 1) ? Bb1 : Bb0;
        char* An = (t & 1) ? Ab0 : Ab1;
        char* Bn = (t & 1) ? Bb0 : Bb1;

        if (t < 11) {
            LOAD_A(t + 1);       // px f32 -> regs, in flight over MFMAs
            STAGE_B(Bn, t + 1);  // bf16 W -> LDS direct
        }

        bf8 a0[4][2], b0[4][2];
#pragma unroll
        for (int mi = 0; mi < 4; ++mi) {
            int r = wr + mi * 16 + rsel;
#pragma unroll
            for (int ks = 0; ks < 2; ++ks) {
                int cst = (ks * 4 + hk) ^ (r & 7);
                a0[mi][ks] = *(const bf8*)(Ac + r * 128 + cst * 16);
            }
        }
#pragma unroll
        for (int ni = 0; ni < 4; ++ni) {
            int r = wc + ni * 16 + rsel;
#pragma unroll
            for (int ks = 0; ks < 2; ++ks) {
                int cst = (ks * 4 + hk) ^ (r & 7);
                b0[ni][ks] = *(const bf8*)(Bc + r * 128 + cst * 16);
            }
        }
#pragma unroll
        for (int mi = 0; mi < 4; ++mi)
#pragma unroll
            for (int ni = 0; ni < 4; ++ni) {
                acc[mi][ni] = MFMA16(a0[mi][0], b0[ni][0], acc[mi][ni]);
                acc[mi][ni] = MFMA16(a0[mi][1], b0[ni][1], acc[mi][ni]);
            }

        if (t < 11) {
            WRITE_A(An);         // cvt + swizzled ds_write (after MFMAs)
            __syncthreads();     // vmcnt(0)+lgkmcnt(0)+barrier
        }
    }

    // ---- epilogue: hoisted div, per-ni const folds ----
    const int lr = (lane >> 4) * 4;
    const int lc = lane & 15;
    int gnv[4]; float cv[4];
#pragma unroll
    for (int ni = 0; ni < 4; ++ni) {
        gnv[ni] = tile_n + wc + ni * 16 + lc;
        cv[ni] = conv_b[gnv[ni]] + mod[768 + gnv[ni]];
    }
#pragma unroll
    for (int mi = 0; mi < 4; ++mi) {
        int gm0 = tile_m + wr + mi * 16 + lr;
        int bimg0 = gm0 / 576;
        int pp0 = gm0 - bimg0 * 576;
#pragma unroll
        for (int r = 0; r < 4; ++r) {
            int bimg = bimg0, pp2 = pp0 + r;
            if (pp2 >= 576) { bimg++; pp2 -= 576; }
            const float* vp = vis_pos + (size_t)(pp2 + 1) * 768;
            float* op = out + ((size_t)bimg * SEQ + 1 + LSEQ + pp2) * 768;
#pragma unroll
            for (int ni = 0; ni < 4; ++ni)
                op[gnv[ni]] = acc[mi][ni][r] + cv[ni] + vp[gnv[ni]];
        }
    }
}

extern "C" void kernel_launch(void* const* d_in, const int* in_sizes, int n_in,
                              void* d_out, int out_size, void* d_ws, size_t ws_size,
                              hipStream_t stream) {
    const int*   ids  = (const int*)d_in[0];
    const int*   am   = (const int*)d_in[1];
    const int*   tti  = (const int*)d_in[2];
    const float* px   = (const float*)d_in[3];
    const float* we   = (const float*)d_in[5];
    const float* pe   = (const float*)d_in[6];
    const float* tke  = (const float*)d_in[7];
    const float* lng  = (const float*)d_in[8];
    const float* lnb  = (const float*)d_in[9];
    const float* cw   = (const float*)d_in[10];
    const float* cb   = (const float*)d_in[11];
    const float* cls  = (const float*)d_in[12];
    const float* vpos = (const float*)d_in[13];
    const float* mod  = (const float*)d_in[14];
    float* out = (float*)d_out;

    __bf16* Wbf = (__bf16*)d_ws;

    hipFuncSetAttribute((const void*)gemm_patch,
                        hipFuncAttributeMaxDynamicSharedMemorySize, GEMM_LDS);

    prep_kernel<<<1275, 256, 0, stream>>>(cw, (unsigned short*)Wbf, ids, tti,
                                          we, pe, tke, lng, lnb, mod, cls, am, out);
    gemm_patch<<<1728, 256, GEMM_LDS, stream>>>(px, Wbf, cb, vpos, mod, out);
}

// Round 14
// 97.923 us; speedup vs baseline: 1.9947x; 1.2206x over previous
//
#include <hip/hip_runtime.h>

typedef __attribute__((ext_vector_type(4))) float f4;
typedef __attribute__((ext_vector_type(4))) float f32x4;
typedef __attribute__((ext_vector_type(8))) __bf16 bf8;
typedef __attribute__((ext_vector_type(8))) unsigned short us8;

#define NB 64
#define LSEQ 40
#define D_DIM 768
#define NPATCH 576
#define SEQ 617
#define K_DIM 768
#define M_DIM (NB * NPATCH)   // 36864
#define GEMM_LDS 131072

static __device__ __forceinline__ unsigned short f2bf(float f) {
    union { float f; unsigned u; } v; v.f = f;
    unsigned r = v.u + 0x7FFFu + ((v.u >> 16) & 1u);
    return (unsigned short)(r >> 16);
}

static __device__ __forceinline__ void gload_lds16(const void* g, void* l) {
    __builtin_amdgcn_global_load_lds(
        (const __attribute__((address_space(1))) unsigned int*)g,
        (__attribute__((address_space(3))) unsigned int*)l,
        16, 0, 0);
}

#define MFMA16(a, b, c) __builtin_amdgcn_mfma_f32_16x16x32_bf16((a), (b), (c), 0, 0, 0)

// ---- prep: convert_w only (f32 -> bf16, chunk-swizzled) ----
// stored[n][blk][c] = logical[n][blk][c ^ (n&7)], 16B chunks, 128B blocks.
__global__ __launch_bounds__(256) void prep_w(const float* __restrict__ cw,
                                              unsigned short* __restrict__ wo) {
    int t = blockIdx.x * 256 + threadIdx.x;   // 73728 chunk-threads
    int cs = t % 96, n = t / 96;
    int blk8 = cs >> 3, c = cs & 7;
    int cl = (blk8 << 3) | (c ^ (n & 7));
    const float* s = cw + (size_t)n * 768 + cl * 8;
    f4 a = *(const f4*)s;
    f4 b = *(const f4*)(s + 4);
    us8 r;
    r[0]=f2bf(a[0]); r[1]=f2bf(a[1]); r[2]=f2bf(a[2]); r[3]=f2bf(a[3]);
    r[4]=f2bf(b[0]); r[5]=f2bf(b[1]); r[6]=f2bf(b[2]); r[7]=f2bf(b[3]);
    *(us8*)(wo + (size_t)n * 768 + cs * 8) = r;
}

// ---- fused GEMM (R10 config, best measured) + post-epilogue text/cls ----
// GEMM: 256x256, BK=64, 8 waves, depth-1 reg-staged A from pixel_values,
// B via global_load_lds from pre-swizzled bf16 W, one __syncthreads/tile.
// After the GEMM epilogue (acc dead): each wave handles one text row
// (blockIdx.x*8+w < 2560) with gather+LN+mod; then a guarded flat pass
// writes CLS rows + masks. No live-range overlap with the K-loop.
__global__ __launch_bounds__(512, 2) void gemm_patch(
    const float* __restrict__ px, const __bf16* __restrict__ W,
    const float* __restrict__ conv_b, const float* __restrict__ vis_pos,
    const float* __restrict__ mod, float* __restrict__ out,
    const int* __restrict__ ids, const int* __restrict__ tti,
    const float* __restrict__ we, const float* __restrict__ pe,
    const float* __restrict__ tke, const float* __restrict__ lng,
    const float* __restrict__ lnb, const float* __restrict__ cls,
    const int* __restrict__ am) {
    extern __shared__ __align__(16) char smem[];   // 128 KB
    char* Ab0 = smem;            // A buffers: 256 rows x 128 B
    char* Ab1 = smem + 32768;
    char* Bb0 = smem + 65536;    // B buffers
    char* Bb1 = smem + 98304;

    const int tid = threadIdx.x;
    const int w = tid >> 6, lane = tid & 63;

    // bijective XCD remap: 432 blocks = 8 XCDs * 54
    int lid = blockIdx.x;
    int gwi = (lid & 7) * 54 + (lid >> 3);
    const int tile_n = (gwi % 3) * 256;
    const int tile_m = (gwi / 3) * 256;
    const int wm = w >> 2, wn = w & 3;
    const int wr = wm * 128, wc = wn * 64;

    f32x4 acc[8][4] = {};
    const char* Bb = (const char*)W;
    const int rsel = lane & 15;
    const int hk = lane >> 4;

    // ---- A-staging lane geometry (constant across tiles) ----
    const int arow = tid & 255;          // A-tile row this thread stages
    const int ii0 = tid >> 8;            // half selector
    int agm = tile_m + arow;
    int abimg = agm / 576, ap = agm % 576;
    int aph = ap / 24, apw = ap % 24;
    const float* pxrow = px + (size_t)abimg * 442368
                            + (size_t)(aph * 16) * 384 + apw * 16;

    f4 areg[2][4];
    auto LOAD_A = [&](int kt) {
        int c = kt >> 2, i0 = (kt & 3) << 2;
#pragma unroll
        for (int rep = 0; rep < 2; ++rep) {
            int i = i0 + ii0 + rep * 2;
            const float* s = pxrow + (size_t)c * 147456 + i * 384;
#pragma unroll
            for (int q = 0; q < 4; ++q) areg[rep][q] = *(const f4*)(s + q * 4);
        }
    };
    auto WRITE_A = [&](char* dst) {
#pragma unroll
        for (int rep = 0; rep < 2; ++rep) {
            int ii = ii0 + rep * 2;
            us8 h0, h1;
#pragma unroll
            for (int q = 0; q < 2; ++q) {
                h0[q*4+0]=f2bf(areg[rep][q][0]); h0[q*4+1]=f2bf(areg[rep][q][1]);
                h0[q*4+2]=f2bf(areg[rep][q][2]); h0[q*4+3]=f2bf(areg[rep][q][3]);
                h1[q*4+0]=f2bf(areg[rep][q+2][0]); h1[q*4+1]=f2bf(areg[rep][q+2][1]);
                h1[q*4+2]=f2bf(areg[rep][q+2][2]); h1[q*4+3]=f2bf(areg[rep][q+2][3]);
            }
            int cc0 = ii * 2;
            *(us8*)(dst + arow * 128 + ((cc0    ) ^ (arow & 7)) * 16) = h0;
            *(us8*)(dst + arow * 128 + ((cc0 + 1) ^ (arow & 7)) * 16) = h1;
        }
    };
    auto STAGE_B = [&](char* lbase, int kt) {
#pragma unroll
        for (int i = 0; i < 4; ++i) {
            int uoff = (w << 10) + i * 8192;       // wave-uniform
            int loff = uoff + (lane << 4);
            int row = loff >> 7, col = loff & 127;
            gload_lds16(Bb + (size_t)(tile_n + row) * 1536 + kt * 128 + col,
                        lbase + uoff);
        }
    };

    // prologue: tile 0
    LOAD_A(0);
    STAGE_B(Bb0, 0);
    WRITE_A(Ab0);            // compiler inserts vmcnt wait for areg
    __syncthreads();         // drains B gload_lds + A ds_writes

    for (int t = 0; t < 12; ++t) {
        char* Ac = (t & 1) ? Ab1 : Ab0;
        char* Bc = (t & 1) ? Bb1 : Bb0;
        char* An = (t & 1) ? Ab0 : Ab1;
        char* Bn = (t & 1) ? Bb0 : Bb1;

        if (t < 11) {
            LOAD_A(t + 1);       // f32 pixel loads -> regs, in flight over MFMAs
            STAGE_B(Bn, t + 1);  // bf16 W -> LDS direct
        }

        bf8 a0[4][2], b0[4][2];
#pragma unroll
        for (int mi = 0; mi < 4; ++mi) {
            int r = wr + mi * 16 + rsel;
#pragma unroll
            for (int ks = 0; ks < 2; ++ks) {
                int cst = (ks * 4 + hk) ^ (r & 7);
                a0[mi][ks] = *(const bf8*)(Ac + r * 128 + cst * 16);
            }
        }
#pragma unroll
        for (int ni = 0; ni < 4; ++ni) {
            int r = wc + ni * 16 + rsel;
#pragma unroll
            for (int ks = 0; ks < 2; ++ks) {
                int cst = (ks * 4 + hk) ^ (r & 7);
                b0[ni][ks] = *(const bf8*)(Bc + r * 128 + cst * 16);
            }
        }
#pragma unroll
        for (int mi = 0; mi < 4; ++mi)
#pragma unroll
            for (int ni = 0; ni < 4; ++ni) {
                acc[mi][ni] = MFMA16(a0[mi][0], b0[ni][0], acc[mi][ni]);
                acc[mi][ni] = MFMA16(a0[mi][1], b0[ni][1], acc[mi][ni]);
            }

        bf8 a1[4][2];
#pragma unroll
        for (int mi = 0; mi < 4; ++mi) {
            int r = wr + 64 + mi * 16 + rsel;
#pragma unroll
            for (int ks = 0; ks < 2; ++ks) {
                int cst = (ks * 4 + hk) ^ (r & 7);
                a1[mi][ks] = *(const bf8*)(Ac + r * 128 + cst * 16);
            }
        }
#pragma unroll
        for (int mi = 0; mi < 4; ++mi)
#pragma unroll
            for (int ni = 0; ni < 4; ++ni) {
                acc[4 + mi][ni] = MFMA16(a1[mi][0], b0[ni][0], acc[4 + mi][ni]);
                acc[4 + mi][ni] = MFMA16(a1[mi][1], b0[ni][1], acc[4 + mi][ni]);
            }

        if (t < 11) {
            WRITE_A(An);         // cvt + swizzled ds_write (after MFMAs)
            __syncthreads();     // vmcnt(0)+lgkmcnt(0)+barrier: all staged
        }
    }

    // ---- epilogue: hoisted div, per-ni const folds ----
    {
        const int lr = (lane >> 4) * 4;
        const int lc = lane & 15;
        int gnv[4]; float cv[4];
#pragma unroll
        for (int ni = 0; ni < 4; ++ni) {
            gnv[ni] = tile_n + wc + ni * 16 + lc;
            cv[ni] = conv_b[gnv[ni]] + mod[768 + gnv[ni]];
        }
#pragma unroll
        for (int mi = 0; mi < 8; ++mi) {
            int gm0 = tile_m + wr + mi * 16 + lr;
            int bimg0 = gm0 / 576;
            int pp0 = gm0 - bimg0 * 576;
#pragma unroll
            for (int r = 0; r < 4; ++r) {
                int bimg = bimg0, pp2 = pp0 + r;
                if (pp2 >= 576) { bimg++; pp2 -= 576; }
                const float* vp = vis_pos + (size_t)(pp2 + 1) * 768;
                float* op = out + ((size_t)bimg * SEQ + 1 + LSEQ + pp2) * 768;
#pragma unroll
                for (int ni = 0; ni < 4; ++ni)
                    op[gnv[ni]] = acc[mi][ni][r] + cv[ni] + vp[gnv[ni]];
            }
        }
    }

    // ---- appended: text rows (1 per wave; 432*8 = 3456 slots >= 2560) ----
    {
        int row = blockIdx.x * 8 + w;
        if (row < 2560) {
            int b = row / 40, l = row % 40;
            const float* wp = we + (size_t)ids[row] * 768;
            const float* pp = pe + l * 768;
            const float* tp = tke + (size_t)tti[row] * 768;
            f4 x[3];
            float s = 0.f, q = 0.f;
#pragma unroll
            for (int j = 0; j < 3; ++j) {
                int d = j * 256 + lane * 4;
                f4 v = *(const f4*)(wp + d);
                f4 v2 = *(const f4*)(pp + d);
                f4 v3 = *(const f4*)(tp + d);
                v = v + v2 + v3;
                x[j] = v;
                s += v[0] + v[1] + v[2] + v[3];
                q += v[0]*v[0] + v[1]*v[1] + v[2]*v[2] + v[3]*v[3];
            }
#pragma unroll
            for (int o = 32; o > 0; o >>= 1) { s += __shfl_xor(s, o); q += __shfl_xor(q, o); }
            float mean = s * (1.0f / 768.0f);
            float var = q * (1.0f / 768.0f) - mean * mean;
            float rstd = rsqrtf(var + 1e-12f);
            float* op = out + ((size_t)b * SEQ + 1 + l) * 768;
#pragma unroll
            for (int j = 0; j < 3; ++j) {
                int d = j * 256 + lane * 4;
                f4 gg = *(const f4*)(lng + d);
                f4 bv = *(const f4*)(lnb + d);
                f4 mm = *(const f4*)(mod + d);
                f4 r = (x[j] - mean) * rstd * gg + bv + mm;
                *(f4*)(op + d) = r;
            }
        }
    }

    // ---- appended: CLS rows + masks (guarded flat pass) ----
    {
        int t2 = blockIdx.x * 512 + tid;     // 221184 threads >= 88640 elems
        if (t2 < NB * 768) {
            int b = t2 / 768, d = t2 % 768;
            out[(size_t)b * SEQ * 768 + d] = cls[d];
        } else if (t2 < NB * 768 + NB * SEQ) {
            int i = t2 - NB * 768;
            int b = i / SEQ, s = i % SEQ;
            float v = 1.0f;
            if (s >= 1 && s <= LSEQ) v = (float)am[b * LSEQ + s - 1];
            out[(size_t)NB * SEQ * 768 + i] = v;
        }
    }
}

extern "C" void kernel_launch(void* const* d_in, const int* in_sizes, int n_in,
                              void* d_out, int out_size, void* d_ws, size_t ws_size,
                              hipStream_t stream) {
    const int*   ids  = (const int*)d_in[0];
    const int*   am   = (const int*)d_in[1];
    const int*   tti  = (const int*)d_in[2];
    const float* px   = (const float*)d_in[3];
    const float* we   = (const float*)d_in[5];
    const float* pe   = (const float*)d_in[6];
    const float* tke  = (const float*)d_in[7];
    const float* lng  = (const float*)d_in[8];
    const float* lnb  = (const float*)d_in[9];
    const float* cw   = (const float*)d_in[10];
    const float* cb   = (const float*)d_in[11];
    const float* cls  = (const float*)d_in[12];
    const float* vpos = (const float*)d_in[13];
    const float* mod  = (const float*)d_in[14];
    float* out = (float*)d_out;

    __bf16* Wbf = (__bf16*)d_ws;

    hipFuncSetAttribute((const void*)gemm_patch,
                        hipFuncAttributeMaxDynamicSharedMemorySize, GEMM_LDS);

    prep_w<<<288, 256, 0, stream>>>(cw, (unsigned short*)Wbf);
    gemm_patch<<<432, 512, GEMM_LDS, stream>>>(px, Wbf, cb, vpos, mod, out,
                                               ids, tti, we, pe, tke, lng, lnb,
                                               cls, am);
}